// Round 1
// baseline (654.040 us; speedup 1.0000x reference)
//
#include <hip/hip_runtime.h>

#define FEATN 128
#define F3 384
#define BM 32
#define TABN 2048
#define D0 0.1f
#define CUT 5.0f
#define PI_F 3.14159265358979323846f

// ---------------------------------------------------------------------------
// Kernel 1: build w_s lookup table: tab[i][j] = (rbf(d_i) @ Wd + bd)[j] * env(d_i)
// d_i = D0 + i * (CUT-D0)/(TABN-1),  i in [0, TABN)
// ---------------------------------------------------------------------------
__global__ __launch_bounds__(F3) void table_kernel(const float* __restrict__ Wd,
                                                   const float* __restrict__ bd,
                                                   float* __restrict__ tab) {
  __shared__ float rbf_s[20];
  const int i = blockIdx.x;
  const int j = threadIdx.x;
  const float hstep = (CUT - D0) / (float)(TABN - 1);
  const float d = D0 + hstep * (float)i;
  if (j < 20) {
    const float kk = (float)(j + 1);
    rbf_s[j] = sinf(kk * (PI_F / CUT) * d) / d;
  }
  __syncthreads();
  const float env = 0.5f * (cosf((PI_F / CUT) * d) + 1.0f);
  float acc = bd[j];
#pragma unroll
  for (int k = 0; k < 20; ++k) acc = fmaf(rbf_s[k], Wd[k * F3 + j], acc);
  tab[i * F3 + j] = acc * env;
}

// ---------------------------------------------------------------------------
// Kernel 2: fused node transform: h = silu(s @ W1 + b1) @ W2 + b2
// Block: 256 threads, BM=32 rows. f32 vector-ALU GEMM (no fp32 MFMA on CDNA4).
// ---------------------------------------------------------------------------
__global__ __launch_bounds__(256, 2) void node_kernel(
    const float* __restrict__ s, const float* __restrict__ W1,
    const float* __restrict__ b1, const float* __restrict__ W2,
    const float* __restrict__ b2, float* __restrict__ h, int n) {
  __shared__ float s_s[BM][FEATN + 1];
  __shared__ float t_s[BM][FEATN + 1];
  const int tid = threadIdx.x;
  const int row0 = blockIdx.x * BM;

  // stage s rows (float4, zero-fill OOB rows)
  for (int i = tid; i < BM * (FEATN / 4); i += 256) {
    const int r = i >> 5;          // 32 float4 per row
    const int c = (i & 31) << 2;
    float4 v = make_float4(0.f, 0.f, 0.f, 0.f);
    if (row0 + r < n) v = *(const float4*)&s[(size_t)(row0 + r) * FEATN + c];
    s_s[r][c + 0] = v.x; s_s[r][c + 1] = v.y;
    s_s[r][c + 2] = v.z; s_s[r][c + 3] = v.w;
  }
  __syncthreads();

  // GEMM1 + silu -> t_s.  thread = (rg: 16 groups x 2 rows, cg: 16 groups x 8 cols)
  {
    const int rg = tid >> 4;
    const int cg = tid & 15;
    float acc[2][8];
#pragma unroll
    for (int r = 0; r < 2; ++r)
#pragma unroll
      for (int c = 0; c < 8; ++c) acc[r][c] = 0.f;

#pragma unroll 4
    for (int k = 0; k < FEATN; ++k) {
      const float a0 = s_s[rg * 2 + 0][k];
      const float a1 = s_s[rg * 2 + 1][k];
      const float* wr = &W1[k * FEATN + cg * 8];
      const float4 w0 = *(const float4*)(wr);
      const float4 w1 = *(const float4*)(wr + 4);
      const float wv[8] = {w0.x, w0.y, w0.z, w0.w, w1.x, w1.y, w1.z, w1.w};
#pragma unroll
      for (int c = 0; c < 8; ++c) {
        acc[0][c] = fmaf(a0, wv[c], acc[0][c]);
        acc[1][c] = fmaf(a1, wv[c], acc[1][c]);
      }
    }
#pragma unroll
    for (int r = 0; r < 2; ++r)
#pragma unroll
      for (int c = 0; c < 8; ++c) {
        const float v = acc[r][c] + b1[cg * 8 + c];
        const float t = v / (1.0f + __expf(-v));  // silu
        t_s[rg * 2 + r][cg * 8 + c] = t;
      }
  }
  __syncthreads();

  // GEMM2 + bias -> h.  thread = (rg: 8 groups x 4 rows, cg: 32 groups x 12 cols)
  {
    const int rg = tid >> 5;
    const int cg = tid & 31;
    float acc[4][12];
#pragma unroll
    for (int r = 0; r < 4; ++r)
#pragma unroll
      for (int c = 0; c < 12; ++c) acc[r][c] = 0.f;

#pragma unroll 2
    for (int k = 0; k < FEATN; ++k) {
      float a[4];
#pragma unroll
      for (int r = 0; r < 4; ++r) a[r] = t_s[rg * 4 + r][k];
      const float* wr = &W2[k * F3 + cg * 12];
      const float4 w0 = *(const float4*)(wr);
      const float4 w1 = *(const float4*)(wr + 4);
      const float4 w2 = *(const float4*)(wr + 8);
      const float wv[12] = {w0.x, w0.y, w0.z, w0.w, w1.x, w1.y,
                            w1.z, w1.w, w2.x, w2.y, w2.z, w2.w};
#pragma unroll
      for (int r = 0; r < 4; ++r)
#pragma unroll
        for (int c = 0; c < 12; ++c)
          acc[r][c] = fmaf(a[r], wv[c], acc[r][c]);
    }

    float bb[12];
#pragma unroll
    for (int c = 0; c < 12; ++c) bb[c] = b2[cg * 12 + c];

#pragma unroll
    for (int r = 0; r < 4; ++r) {
      const int row = row0 + rg * 4 + r;
      if (row < n) {
        float* op = &h[(size_t)row * F3 + cg * 12];
        float4 o0, o1, o2;
        o0.x = acc[r][0] + bb[0];  o0.y = acc[r][1] + bb[1];
        o0.z = acc[r][2] + bb[2];  o0.w = acc[r][3] + bb[3];
        o1.x = acc[r][4] + bb[4];  o1.y = acc[r][5] + bb[5];
        o1.z = acc[r][6] + bb[6];  o1.w = acc[r][7] + bb[7];
        o2.x = acc[r][8] + bb[8];  o2.y = acc[r][9] + bb[9];
        o2.z = acc[r][10] + bb[10]; o2.w = acc[r][11] + bb[11];
        *(float4*)(op + 0) = o0;
        *(float4*)(op + 4) = o1;
        *(float4*)(op + 8) = o2;
      }
    }
  }
}

// ---------------------------------------------------------------------------
// Kernel 3: edge kernel. One float4 of one edge-row per thread (96 per edge).
// out[e][q] = h[nbr][q] * lerp(tab[i0][q], tab[i0+1][q], fr)
// ---------------------------------------------------------------------------
__global__ __launch_bounds__(256) void edge_kernel(
    const float* __restrict__ dist, const int* __restrict__ nbrs,
    const float* __restrict__ h, const float* __restrict__ tab,
    float4* __restrict__ out, int n_edges) {
  const int gid = blockIdx.x * 256 + threadIdx.x;
  const int total = n_edges * 96;
  if (gid >= total) return;
  const int e = gid / 96;               // magic-mul div by constant
  const int q = gid - e * 96;

  const float d = dist[e];
  const int nbr = nbrs[2 * e + 1];

  const float inv_h = (float)(TABN - 1) / (CUT - D0);
  float x = (d - D0) * inv_h;
  x = fminf(fmaxf(x, 0.0f), 2046.9995f);
  const int i0 = (int)x;
  const float fr = x - (float)i0;

  const float4* tp = (const float4*)tab + (size_t)i0 * 96 + q;
  const float4 t0 = tp[0];
  const float4 t1 = tp[96];
  const float4 ph = *((const float4*)h + (size_t)nbr * 96 + q);

  float4 o;
  o.x = ph.x * fmaf(fr, t1.x - t0.x, t0.x);
  o.y = ph.y * fmaf(fr, t1.y - t0.y, t0.y);
  o.z = ph.z * fmaf(fr, t1.z - t0.z, t0.z);
  o.w = ph.w * fmaf(fr, t1.w - t0.w, t0.w);
  out[gid] = o;
}

// ---------------------------------------------------------------------------
extern "C" void kernel_launch(void* const* d_in, const int* in_sizes, int n_in,
                              void* d_out, int out_size, void* d_ws, size_t ws_size,
                              hipStream_t stream) {
  const float* s_j  = (const float*)d_in[0];
  const float* dist = (const float*)d_in[1];
  const int*   nbrs = (const int*)d_in[2];
  const float* W1   = (const float*)d_in[3];
  const float* b1   = (const float*)d_in[4];
  const float* W2   = (const float*)d_in[5];
  const float* b2   = (const float*)d_in[6];
  const float* Wd   = (const float*)d_in[7];
  const float* bd   = (const float*)d_in[8];
  float* out = (float*)d_out;

  const int n_nodes = in_sizes[0] / FEATN;
  const int n_edges = in_sizes[1];

  float* tab = (float*)d_ws;
  float* h = (float*)((char*)d_ws + (size_t)TABN * F3 * sizeof(float));

  hipLaunchKernelGGL(table_kernel, dim3(TABN), dim3(F3), 0, stream, Wd, bd, tab);
  hipLaunchKernelGGL(node_kernel, dim3((n_nodes + BM - 1) / BM), dim3(256), 0, stream,
                     s_j, W1, b1, W2, b2, h, n_nodes);

  const long long total = (long long)n_edges * 96LL;
  const int blocks = (int)((total + 255) / 256);
  hipLaunchKernelGGL(edge_kernel, dim3(blocks), dim3(256), 0, stream,
                     dist, nbrs, h, tab, (float4*)out, n_edges);
}

// Round 3
// 509.447 us; speedup vs baseline: 1.2838x; 1.2838x over previous
//
#include <hip/hip_runtime.h>

#define FEATN 128
#define F3 384
#define TABN 2048
#define D0 0.1f
#define CUT 5.0f
#define PI_F 3.14159265358979323846f

typedef __attribute__((ext_vector_type(8))) short short8;
typedef __attribute__((ext_vector_type(4))) float f32x4;

__device__ __forceinline__ unsigned short f2bf(float f) {
  unsigned int u = __float_as_uint(f);
  u += 0x7FFFu + ((u >> 16) & 1u);   // round-to-nearest-even
  return (unsigned short)(u >> 16);
}

// XOR swizzle for [R][128]-bf16 LDS tiles: spreads 16B slots across banks (G4)
__device__ __forceinline__ int swz(int row, int col) {
  return row * 128 + (col ^ ((row & 7) << 3));
}

// ---------------------------------------------------------------------------
// Kernel 1: w_s lookup table: tab[i][j] = (rbf(d_i) @ Wd + bd)[j] * env(d_i)
// ---------------------------------------------------------------------------
__global__ __launch_bounds__(F3) void table_kernel(const float* __restrict__ Wd,
                                                   const float* __restrict__ bd,
                                                   float* __restrict__ tab) {
  __shared__ float rbf_s[20];
  const int i = blockIdx.x;
  const int j = threadIdx.x;
  const float hstep = (CUT - D0) / (float)(TABN - 1);
  const float d = D0 + hstep * (float)i;
  if (j < 20) {
    const float kk = (float)(j + 1);
    rbf_s[j] = sinf(kk * (PI_F / CUT) * d) / d;
  }
  __syncthreads();
  const float env = 0.5f * (cosf((PI_F / CUT) * d) + 1.0f);
  float acc = bd[j];
#pragma unroll
  for (int k = 0; k < 20; ++k) acc = fmaf(rbf_s[k], Wd[k * F3 + j], acc);
  tab[i * F3 + j] = acc * env;
}

// ---------------------------------------------------------------------------
// Kernel 2: one-off weight prep: W1t[n][k] = bf16(W1[k][n]), W2t[n][k] = bf16(W2[k][n])
// ---------------------------------------------------------------------------
__global__ __launch_bounds__(256) void prep_kernel(const float* __restrict__ W1,
                                                   const float* __restrict__ W2,
                                                   unsigned short* __restrict__ W1t,
                                                   unsigned short* __restrict__ W2t) {
  const int idx = blockIdx.x * 256 + threadIdx.x;
  if (idx < FEATN * FEATN) {
    const int nn = idx >> 7, k = idx & 127;
    W1t[idx] = f2bf(W1[k * FEATN + nn]);
  }
  const int idx2 = idx - FEATN * FEATN;
  if (idx2 >= 0 && idx2 < F3 * FEATN) {
    const int nn = idx2 >> 7, k = idx2 & 127;
    W2t[idx2] = f2bf(W2[k * F3 + nn]);
  }
}

// ---------------------------------------------------------------------------
// Kernel 3: fused node transform via bf16 MFMA:
//   h = silu(s @ W1 + b1) @ W2 + b2
// 64 rows/block, 4 waves; each wave owns a 16-row strip.
// ---------------------------------------------------------------------------
__global__ __launch_bounds__(256, 2) void node_mfma_kernel(
    const float* __restrict__ s, const unsigned short* __restrict__ W1t,
    const float* __restrict__ b1, const unsigned short* __restrict__ W2t,
    const float* __restrict__ b2, float* __restrict__ h, int n) {
  __shared__ unsigned short sA[64 * 128];   // 16 KB, swizzled
  __shared__ unsigned short sT[64 * 128];   // 16 KB, swizzled
  __shared__ unsigned short sW[128 * 128];  // 32 KB, swizzled (W1t, then W2t chunks)

  const int tid = threadIdx.x;
  const int w = tid >> 6;
  const int lane = tid & 63;
  const int row0 = blockIdx.x * 64;

  // ---- stage s rows (f32 -> bf16), swizzled
#pragma unroll
  for (int i = 0; i < 8; ++i) {
    const int f = i * 256 + tid;   // float4 index in [0,2048)
    const int r = f >> 5;          // 32 float4 per row
    const int c4 = f & 31;
    float4 v = make_float4(0.f, 0.f, 0.f, 0.f);
    if (row0 + r < n) v = *(const float4*)&s[(size_t)(row0 + r) * FEATN + c4 * 4];
    uint2 pk;
    pk.x = (unsigned)f2bf(v.x) | ((unsigned)f2bf(v.y) << 16);
    pk.y = (unsigned)f2bf(v.z) | ((unsigned)f2bf(v.w) << 16);
    *(uint2*)&sA[swz(r, c4 * 4)] = pk;
  }
  // ---- stage W1t (bf16), swizzled
#pragma unroll
  for (int i = 0; i < 8; ++i) {
    const int f = i * 256 + tid;   // 16B chunk index in [0,2048)
    const int r = f >> 4;          // 16 chunks per 128-col row
    const int c8 = f & 15;
    const uint4 v = *(const uint4*)&W1t[r * 128 + c8 * 8];
    *(uint4*)&sW[swz(r, c8 * 8)] = v;
  }
  __syncthreads();

  const int arow = w * 16 + (lane & 15);
  const int kbase = (lane >> 4) * 8;
  const int drow0 = w * 16 + ((lane >> 4) << 2);
  const int dcol = lane & 15;

  // ---- GEMM1: t = silu(s @ W1 + b1)
  {
    f32x4 acc[8] = {};
#pragma unroll
    for (int ks = 0; ks < 4; ++ks) {
      const int kk = ks * 32 + kbase;
      const short8 a = *(const short8*)&sA[swz(arow, kk)];
#pragma unroll
      for (int nf = 0; nf < 8; ++nf) {
        const short8 b = *(const short8*)&sW[swz(nf * 16 + dcol, kk)];
        acc[nf] = __builtin_amdgcn_mfma_f32_16x16x32_bf16(a, b, acc[nf], 0, 0, 0);
      }
    }
#pragma unroll
    for (int nf = 0; nf < 8; ++nf) {
      const int col = nf * 16 + dcol;
      const float bias = b1[col];
#pragma unroll
      for (int r = 0; r < 4; ++r) {
        const float v = acc[nf][r] + bias;
        const float t = v / (1.0f + __expf(-v));  // silu
        sT[swz(drow0 + r, col)] = f2bf(t);
      }
    }
  }
  __syncthreads();   // all waves done with sW (W1) before overwrite

  // ---- GEMM2: h = t @ W2 + b2, in 3 chunks of 128 cols
  for (int c = 0; c < 3; ++c) {
#pragma unroll
    for (int i = 0; i < 8; ++i) {
      const int f = i * 256 + tid;
      const int r = f >> 4;
      const int c8 = f & 15;
      const uint4 v = *(const uint4*)&W2t[(size_t)(c * 128 + r) * 128 + c8 * 8];
      *(uint4*)&sW[swz(r, c8 * 8)] = v;
    }
    __syncthreads();

    f32x4 acc2[8] = {};
#pragma unroll
    for (int ks = 0; ks < 4; ++ks) {
      const int kk = ks * 32 + kbase;
      const short8 a = *(const short8*)&sT[swz(arow, kk)];
#pragma unroll
      for (int nf = 0; nf < 8; ++nf) {
        const short8 b = *(const short8*)&sW[swz(nf * 16 + dcol, kk)];
        acc2[nf] = __builtin_amdgcn_mfma_f32_16x16x32_bf16(a, b, acc2[nf], 0, 0, 0);
      }
    }
#pragma unroll
    for (int nf = 0; nf < 8; ++nf) {
      const int col = c * 128 + nf * 16 + dcol;
      const float bias = b2[col];
#pragma unroll
      for (int r = 0; r < 4; ++r) {
        const int row = row0 + drow0 + r;
        if (row < n) h[(size_t)row * F3 + col] = acc2[nf][r] + bias;
      }
    }
    __syncthreads();   // before next chunk overwrites sW
  }
}

// ---------------------------------------------------------------------------
// Kernel 4: edge kernel. One float4 of one edge-row per thread (96 per edge).
// out[e][q] = h[nbr][q] * lerp(tab[i0][q], tab[i0+1][q], fr)
// Nontemporal store: out is write-once, keep it out of L2/L3 so h/tab stay hot.
// ---------------------------------------------------------------------------
__global__ __launch_bounds__(256) void edge_kernel(
    const float* __restrict__ dist, const int* __restrict__ nbrs,
    const float* __restrict__ h, const float* __restrict__ tab,
    float* __restrict__ out, int n_edges) {
  const int gid = blockIdx.x * 256 + threadIdx.x;
  const int total = n_edges * 96;
  if (gid >= total) return;
  const int e = gid / 96;
  const int q = gid - e * 96;

  const float d = dist[e];
  const int nbr = nbrs[2 * e + 1];

  const float inv_h = (float)(TABN - 1) / (CUT - D0);
  float x = (d - D0) * inv_h;
  x = fminf(fmaxf(x, 0.0f), 2046.9995f);
  const int i0 = (int)x;
  const float fr = x - (float)i0;

  const f32x4* tp = (const f32x4*)tab + (size_t)i0 * 96 + q;
  const f32x4 t0 = tp[0];
  const f32x4 t1 = tp[96];
  const f32x4 ph = *((const f32x4*)h + (size_t)nbr * 96 + q);

  f32x4 o;
  o.x = ph.x * fmaf(fr, t1.x - t0.x, t0.x);
  o.y = ph.y * fmaf(fr, t1.y - t0.y, t0.y);
  o.z = ph.z * fmaf(fr, t1.z - t0.z, t0.z);
  o.w = ph.w * fmaf(fr, t1.w - t0.w, t0.w);
  __builtin_nontemporal_store(o, (f32x4*)out + gid);
}

// ---------------------------------------------------------------------------
extern "C" void kernel_launch(void* const* d_in, const int* in_sizes, int n_in,
                              void* d_out, int out_size, void* d_ws, size_t ws_size,
                              hipStream_t stream) {
  const float* s_j  = (const float*)d_in[0];
  const float* dist = (const float*)d_in[1];
  const int*   nbrs = (const int*)d_in[2];
  const float* W1   = (const float*)d_in[3];
  const float* b1   = (const float*)d_in[4];
  const float* W2   = (const float*)d_in[5];
  const float* b2   = (const float*)d_in[6];
  const float* Wd   = (const float*)d_in[7];
  const float* bd   = (const float*)d_in[8];
  float* out = (float*)d_out;

  const int n_nodes = in_sizes[0] / FEATN;
  const int n_edges = in_sizes[1];

  char* ws = (char*)d_ws;
  float* tab = (float*)ws;                                   // 3,145,728 B
  float* h = (float*)(ws + (size_t)TABN * F3 * 4);           // 76,800,000 B
  unsigned short* W1t = (unsigned short*)(ws + (size_t)TABN * F3 * 4 + (size_t)n_nodes * F3 * 4);
  unsigned short* W2t = W1t + FEATN * FEATN;

  hipLaunchKernelGGL(table_kernel, dim3(TABN), dim3(F3), 0, stream, Wd, bd, tab);
  hipLaunchKernelGGL(prep_kernel, dim3((FEATN * FEATN + F3 * FEATN + 255) / 256), dim3(256),
                     0, stream, W1, W2, W1t, W2t);
  hipLaunchKernelGGL(node_mfma_kernel, dim3((n_nodes + 63) / 64), dim3(256), 0, stream,
                     s_j, W1t, b1, W2t, b2, h, n_nodes);

  const long long total = (long long)n_edges * 96LL;
  const int blocks = (int)((total + 255) / 256);
  hipLaunchKernelGGL(edge_kernel, dim3(blocks), dim3(256), 0, stream,
                     dist, nbrs, h, tab, out, n_edges);
}

// Round 4
// 468.765 us; speedup vs baseline: 1.3952x; 1.0868x over previous
//
#include <hip/hip_runtime.h>

#define FEATN 128
#define F3 384
#define TABN 2048
#define D0 0.1f
#define CUT 5.0f
#define PI_F 3.14159265358979323846f

typedef __attribute__((ext_vector_type(8))) short short8;
typedef __attribute__((ext_vector_type(4))) float f32x4;
typedef __attribute__((ext_vector_type(2))) unsigned int u32x2;

__device__ __forceinline__ unsigned short f2bf(float f) {
  unsigned int u = __float_as_uint(f);
  u += 0x7FFFu + ((u >> 16) & 1u);   // round-to-nearest-even
  return (unsigned short)(u >> 16);
}
__device__ __forceinline__ float bflo(unsigned int u) { return __uint_as_float(u << 16); }
__device__ __forceinline__ float bfhi(unsigned int u) { return __uint_as_float(u & 0xffff0000u); }

// XOR swizzle for [R][128]-bf16 LDS tiles: spreads 16B slots across banks (G4)
__device__ __forceinline__ int swz(int row, int col) {
  return row * 128 + (col ^ ((row & 7) << 3));
}

// ---------------------------------------------------------------------------
// Kernel 1: w_s lookup table: tab[i][j] = (rbf(d_i) @ Wd + bd)[j] * env(d_i)
// ---------------------------------------------------------------------------
__global__ __launch_bounds__(F3) void table_kernel(const float* __restrict__ Wd,
                                                   const float* __restrict__ bd,
                                                   float* __restrict__ tab) {
  __shared__ float rbf_s[20];
  const int i = blockIdx.x;
  const int j = threadIdx.x;
  const float hstep = (CUT - D0) / (float)(TABN - 1);
  const float d = D0 + hstep * (float)i;
  if (j < 20) {
    const float kk = (float)(j + 1);
    rbf_s[j] = sinf(kk * (PI_F / CUT) * d) / d;
  }
  __syncthreads();
  const float env = 0.5f * (cosf((PI_F / CUT) * d) + 1.0f);
  float acc = bd[j];
#pragma unroll
  for (int k = 0; k < 20; ++k) acc = fmaf(rbf_s[k], Wd[k * F3 + j], acc);
  tab[i * F3 + j] = acc * env;
}

// ---------------------------------------------------------------------------
// Kernel 1b: pack interpolation pairs to bf16:
//   tabP[(i*96+q)*8 + 0..3] = bf16(tab[i][4q..4q+3])
//   tabP[(i*96+q)*8 + 4..7] = bf16(tab[i+1][4q..4q+3])
// One 16B load in the edge kernel replaces two 16B loads 1536B apart.
// ---------------------------------------------------------------------------
__global__ __launch_bounds__(256) void pack_kernel(const float* __restrict__ tab,
                                                   unsigned short* __restrict__ tabP) {
  const int t = blockIdx.x * 256 + threadIdx.x;
  if (t >= TABN * 96) return;
  const int i = t / 96;
  const int q = t - i * 96;
  const int i1 = (i + 1 < TABN) ? i + 1 : i;
  const float4 a = *(const float4*)&tab[(size_t)i * F3 + q * 4];
  const float4 b = *(const float4*)&tab[(size_t)i1 * F3 + q * 4];
  uint4 pk;
  pk.x = (unsigned)f2bf(a.x) | ((unsigned)f2bf(a.y) << 16);
  pk.y = (unsigned)f2bf(a.z) | ((unsigned)f2bf(a.w) << 16);
  pk.z = (unsigned)f2bf(b.x) | ((unsigned)f2bf(b.y) << 16);
  pk.w = (unsigned)f2bf(b.z) | ((unsigned)f2bf(b.w) << 16);
  *(uint4*)&tabP[(size_t)t * 8] = pk;
}

// ---------------------------------------------------------------------------
// Kernel 2: one-off weight prep: W1t[n][k] = bf16(W1[k][n]), W2t[n][k] = bf16(W2[k][n])
// ---------------------------------------------------------------------------
__global__ __launch_bounds__(256) void prep_kernel(const float* __restrict__ W1,
                                                   const float* __restrict__ W2,
                                                   unsigned short* __restrict__ W1t,
                                                   unsigned short* __restrict__ W2t) {
  const int idx = blockIdx.x * 256 + threadIdx.x;
  if (idx < FEATN * FEATN) {
    const int nn = idx >> 7, k = idx & 127;
    W1t[idx] = f2bf(W1[k * FEATN + nn]);
  }
  const int idx2 = idx - FEATN * FEATN;
  if (idx2 >= 0 && idx2 < F3 * FEATN) {
    const int nn = idx2 >> 7, k = idx2 & 127;
    W2t[idx2] = f2bf(W2[k * F3 + nn]);
  }
}

// ---------------------------------------------------------------------------
// Kernel 3: fused node transform via bf16 MFMA:
//   h = silu(s @ W1 + b1) @ W2 + b2   (h stored as bf16)
// 64 rows/block, 4 waves; each wave owns a 16-row strip.
// ---------------------------------------------------------------------------
__global__ __launch_bounds__(256, 2) void node_mfma_kernel(
    const float* __restrict__ s, const unsigned short* __restrict__ W1t,
    const float* __restrict__ b1, const unsigned short* __restrict__ W2t,
    const float* __restrict__ b2, unsigned short* __restrict__ hbf, int n) {
  __shared__ unsigned short sA[64 * 128];   // 16 KB, swizzled
  __shared__ unsigned short sT[64 * 128];   // 16 KB, swizzled
  __shared__ unsigned short sW[128 * 128];  // 32 KB, swizzled (W1t, then W2t chunks)

  const int tid = threadIdx.x;
  const int w = tid >> 6;
  const int lane = tid & 63;
  const int row0 = blockIdx.x * 64;

  // ---- stage s rows (f32 -> bf16), swizzled
#pragma unroll
  for (int i = 0; i < 8; ++i) {
    const int f = i * 256 + tid;   // float4 index in [0,2048)
    const int r = f >> 5;          // 32 float4 per row
    const int c4 = f & 31;
    float4 v = make_float4(0.f, 0.f, 0.f, 0.f);
    if (row0 + r < n) v = *(const float4*)&s[(size_t)(row0 + r) * FEATN + c4 * 4];
    uint2 pk;
    pk.x = (unsigned)f2bf(v.x) | ((unsigned)f2bf(v.y) << 16);
    pk.y = (unsigned)f2bf(v.z) | ((unsigned)f2bf(v.w) << 16);
    *(uint2*)&sA[swz(r, c4 * 4)] = pk;
  }
  // ---- stage W1t (bf16), swizzled
#pragma unroll
  for (int i = 0; i < 8; ++i) {
    const int f = i * 256 + tid;   // 16B chunk index in [0,2048)
    const int r = f >> 4;          // 16 chunks per 128-col row
    const int c8 = f & 15;
    const uint4 v = *(const uint4*)&W1t[r * 128 + c8 * 8];
    *(uint4*)&sW[swz(r, c8 * 8)] = v;
  }
  __syncthreads();

  const int arow = w * 16 + (lane & 15);
  const int kbase = (lane >> 4) * 8;
  const int drow0 = w * 16 + ((lane >> 4) << 2);
  const int dcol = lane & 15;

  // ---- GEMM1: t = silu(s @ W1 + b1)
  {
    f32x4 acc[8] = {};
#pragma unroll
    for (int ks = 0; ks < 4; ++ks) {
      const int kk = ks * 32 + kbase;
      const short8 a = *(const short8*)&sA[swz(arow, kk)];
#pragma unroll
      for (int nf = 0; nf < 8; ++nf) {
        const short8 b = *(const short8*)&sW[swz(nf * 16 + dcol, kk)];
        acc[nf] = __builtin_amdgcn_mfma_f32_16x16x32_bf16(a, b, acc[nf], 0, 0, 0);
      }
    }
#pragma unroll
    for (int nf = 0; nf < 8; ++nf) {
      const int col = nf * 16 + dcol;
      const float bias = b1[col];
#pragma unroll
      for (int r = 0; r < 4; ++r) {
        const float v = acc[nf][r] + bias;
        const float t = v / (1.0f + __expf(-v));  // silu
        sT[swz(drow0 + r, col)] = f2bf(t);
      }
    }
  }
  __syncthreads();   // all waves done with sW (W1) before overwrite

  // ---- GEMM2: h = t @ W2 + b2, in 3 chunks of 128 cols
  for (int c = 0; c < 3; ++c) {
#pragma unroll
    for (int i = 0; i < 8; ++i) {
      const int f = i * 256 + tid;
      const int r = f >> 4;
      const int c8 = f & 15;
      const uint4 v = *(const uint4*)&W2t[(size_t)(c * 128 + r) * 128 + c8 * 8];
      *(uint4*)&sW[swz(r, c8 * 8)] = v;
    }
    __syncthreads();

    f32x4 acc2[8] = {};
#pragma unroll
    for (int ks = 0; ks < 4; ++ks) {
      const int kk = ks * 32 + kbase;
      const short8 a = *(const short8*)&sT[swz(arow, kk)];
#pragma unroll
      for (int nf = 0; nf < 8; ++nf) {
        const short8 b = *(const short8*)&sW[swz(nf * 16 + dcol, kk)];
        acc2[nf] = __builtin_amdgcn_mfma_f32_16x16x32_bf16(a, b, acc2[nf], 0, 0, 0);
      }
    }
#pragma unroll
    for (int nf = 0; nf < 8; ++nf) {
      const int col = c * 128 + nf * 16 + dcol;
      const float bias = b2[col];
#pragma unroll
      for (int r = 0; r < 4; ++r) {
        const int row = row0 + drow0 + r;
        if (row < n) hbf[(size_t)row * F3 + col] = f2bf(acc2[nf][r] + bias);
      }
    }
    __syncthreads();   // before next chunk overwrites sW
  }
}

// ---------------------------------------------------------------------------
// Kernel 4: edge kernel. One float4 of one edge-row per thread (96 per edge).
// out[e][q] = h[nbr][q] * lerp(t0[q], t1[q], fr)
// Reads per thread: 8B bf16 h (nontemporal — don't evict tabP from L2) +
// 16B packed bf16 tab pair + 16B nt write.
// ---------------------------------------------------------------------------
__global__ __launch_bounds__(256) void edge_kernel(
    const float* __restrict__ dist, const int* __restrict__ nbrs,
    const unsigned short* __restrict__ hbf, const unsigned short* __restrict__ tabP,
    float* __restrict__ out, int n_edges) {
  const int gid = blockIdx.x * 256 + threadIdx.x;
  const int total = n_edges * 96;
  if (gid >= total) return;
  const int e = gid / 96;
  const int q = gid - e * 96;

  const float d = dist[e];
  const int nbr = nbrs[2 * e + 1];

  const float inv_h = (float)(TABN - 1) / (CUT - D0);
  float x = (d - D0) * inv_h;
  x = fminf(fmaxf(x, 0.0f), 2046.9995f);
  const int i0 = (int)x;
  const float fr = x - (float)i0;

  const uint4 tp = *(const uint4*)&tabP[((size_t)i0 * 96 + q) * 8];
  const u32x2 hp = __builtin_nontemporal_load(
      (const u32x2*)&hbf[(size_t)nbr * F3 + q * 4]);

  const float t0x = bflo(tp.x), t0y = bfhi(tp.x);
  const float t0z = bflo(tp.y), t0w = bfhi(tp.y);
  const float t1x = bflo(tp.z), t1y = bfhi(tp.z);
  const float t1z = bflo(tp.w), t1w = bfhi(tp.w);

  f32x4 o;
  o.x = bflo(hp.x) * fmaf(fr, t1x - t0x, t0x);
  o.y = bfhi(hp.x) * fmaf(fr, t1y - t0y, t0y);
  o.z = bflo(hp.y) * fmaf(fr, t1z - t0z, t0z);
  o.w = bfhi(hp.y) * fmaf(fr, t1w - t0w, t0w);
  __builtin_nontemporal_store(o, (f32x4*)out + gid);
}

// ---------------------------------------------------------------------------
extern "C" void kernel_launch(void* const* d_in, const int* in_sizes, int n_in,
                              void* d_out, int out_size, void* d_ws, size_t ws_size,
                              hipStream_t stream) {
  const float* s_j  = (const float*)d_in[0];
  const float* dist = (const float*)d_in[1];
  const int*   nbrs = (const int*)d_in[2];
  const float* W1   = (const float*)d_in[3];
  const float* b1   = (const float*)d_in[4];
  const float* W2   = (const float*)d_in[5];
  const float* b2   = (const float*)d_in[6];
  const float* Wd   = (const float*)d_in[7];
  const float* bd   = (const float*)d_in[8];
  float* out = (float*)d_out;

  const int n_nodes = in_sizes[0] / FEATN;
  const int n_edges = in_sizes[1];

  char* ws = (char*)d_ws;
  float* tab = (float*)ws;                                          // 3,145,728 B
  unsigned short* tabP = (unsigned short*)(ws + 3145728);           // 3,145,728 B
  unsigned short* hbf = (unsigned short*)(ws + 2 * 3145728);        // n_nodes*384*2 B
  unsigned short* W1t = hbf + (size_t)n_nodes * F3;
  unsigned short* W2t = W1t + FEATN * FEATN;

  hipLaunchKernelGGL(table_kernel, dim3(TABN), dim3(F3), 0, stream, Wd, bd, tab);
  hipLaunchKernelGGL(prep_kernel, dim3((FEATN * FEATN + F3 * FEATN + 255) / 256), dim3(256),
                     0, stream, W1, W2, W1t, W2t);
  hipLaunchKernelGGL(pack_kernel, dim3((TABN * 96 + 255) / 256), dim3(256), 0, stream,
                     tab, tabP);
  hipLaunchKernelGGL(node_mfma_kernel, dim3((n_nodes + 63) / 64), dim3(256), 0, stream,
                     s_j, W1t, b1, W2t, b2, hbf, n_nodes);

  const long long total = (long long)n_edges * 96LL;
  const int blocks = (int)((total + 255) / 256);
  hipLaunchKernelGGL(edge_kernel, dim3(blocks), dim3(256), 0, stream,
                     dist, nbrs, hbf, tabP, out, n_edges);
}

// Round 5
// 385.140 us; speedup vs baseline: 1.6982x; 1.2171x over previous
//
#include <hip/hip_runtime.h>

#define FEATN 128
#define F3 384
#define TABN 2048
#define D0 0.1f
#define CUT 5.0f
#define PI_F 3.14159265358979323846f

typedef __attribute__((ext_vector_type(8))) short short8;
typedef __attribute__((ext_vector_type(4))) float f32x4;
typedef __attribute__((ext_vector_type(2))) unsigned int u32x2;

__device__ __forceinline__ unsigned short f2bf(float f) {
  unsigned int u = __float_as_uint(f);
  u += 0x7FFFu + ((u >> 16) & 1u);   // round-to-nearest-even
  return (unsigned short)(u >> 16);
}
__device__ __forceinline__ float bflo(unsigned int u) { return __uint_as_float(u << 16); }
__device__ __forceinline__ float bfhi(unsigned int u) { return __uint_as_float(u & 0xffff0000u); }

// XOR swizzle for [R][128]-bf16 LDS tiles: spreads 16B slots across banks (G4)
__device__ __forceinline__ int swz(int row, int col) {
  return row * 128 + (col ^ ((row & 7) << 3));
}

// ---------------------------------------------------------------------------
// Kernel 1: fused table + pack. Block i computes w_s row i (384 cols) in LDS,
// then writes bf16 pair-packed tabP: row i's quads into tabP[i].t0 slots and
// into tabP[i-1].t1 slots (tabP[i] = {t0=row i, t1=row i+1}).
// tabP[(i*96+q)*8 + 0..3] = bf16 row_i[4q..4q+3], + 4..7 = bf16 row_{i+1}[...]
// ---------------------------------------------------------------------------
__global__ __launch_bounds__(F3) void table_kernel(const float* __restrict__ Wd,
                                                   const float* __restrict__ bd,
                                                   unsigned short* __restrict__ tabP) {
  __shared__ float rbf_s[20];
  __shared__ float row[F3];
  const int i = blockIdx.x;
  const int j = threadIdx.x;
  const float hstep = (CUT - D0) / (float)(TABN - 1);
  const float d = D0 + hstep * (float)i;
  if (j < 20) {
    const float kk = (float)(j + 1);
    rbf_s[j] = sinf(kk * (PI_F / CUT) * d) / d;
  }
  __syncthreads();
  const float env = 0.5f * (cosf((PI_F / CUT) * d) + 1.0f);
  float acc = bd[j];
#pragma unroll
  for (int k = 0; k < 20; ++k) acc = fmaf(rbf_s[k], Wd[k * F3 + j], acc);
  row[j] = acc * env;
  __syncthreads();

  if (j < 96) {                 // t0 slots of row i
    const float4 v = *(const float4*)&row[j * 4];
    uint2 pk;
    pk.x = (unsigned)f2bf(v.x) | ((unsigned)f2bf(v.y) << 16);
    pk.y = (unsigned)f2bf(v.z) | ((unsigned)f2bf(v.w) << 16);
    *(uint2*)&tabP[((size_t)i * 96 + j) * 8] = pk;
  } else if (j < 192) {         // t1 slots of row i-1
    if (i > 0) {
      const int q = j - 96;
      const float4 v = *(const float4*)&row[q * 4];
      uint2 pk;
      pk.x = (unsigned)f2bf(v.x) | ((unsigned)f2bf(v.y) << 16);
      pk.y = (unsigned)f2bf(v.z) | ((unsigned)f2bf(v.w) << 16);
      *(uint2*)&tabP[((size_t)(i - 1) * 96 + q) * 8 + 4] = pk;
    }
  }
}

// ---------------------------------------------------------------------------
// Kernel 2: one-off weight prep: W1t[n][k] = bf16(W1[k][n]), W2t[n][k] = bf16(W2[k][n])
// ---------------------------------------------------------------------------
__global__ __launch_bounds__(256) void prep_kernel(const float* __restrict__ W1,
                                                   const float* __restrict__ W2,
                                                   unsigned short* __restrict__ W1t,
                                                   unsigned short* __restrict__ W2t) {
  const int idx = blockIdx.x * 256 + threadIdx.x;
  if (idx < FEATN * FEATN) {
    const int nn = idx >> 7, k = idx & 127;
    W1t[idx] = f2bf(W1[k * FEATN + nn]);
  }
  const int idx2 = idx - FEATN * FEATN;
  if (idx2 >= 0 && idx2 < F3 * FEATN) {
    const int nn = idx2 >> 7, k = idx2 & 127;
    W2t[idx2] = f2bf(W2[k * F3 + nn]);
  }
}

// ---------------------------------------------------------------------------
// Kernel 3: fused node transform via bf16 MFMA:
//   h = silu(s @ W1 + b1) @ W2 + b2   (h stored as bf16)
// 64 rows/block, 4 waves; each wave owns a 16-row strip.
// ---------------------------------------------------------------------------
__global__ __launch_bounds__(256, 2) void node_mfma_kernel(
    const float* __restrict__ s, const unsigned short* __restrict__ W1t,
    const float* __restrict__ b1, const unsigned short* __restrict__ W2t,
    const float* __restrict__ b2, unsigned short* __restrict__ hbf, int n) {
  __shared__ unsigned short sA[64 * 128];   // 16 KB, swizzled
  __shared__ unsigned short sT[64 * 128];   // 16 KB, swizzled
  __shared__ unsigned short sW[128 * 128];  // 32 KB, swizzled (W1t, then W2t chunks)

  const int tid = threadIdx.x;
  const int w = tid >> 6;
  const int lane = tid & 63;
  const int row0 = blockIdx.x * 64;

  // ---- stage s rows (f32 -> bf16), swizzled
#pragma unroll
  for (int i = 0; i < 8; ++i) {
    const int f = i * 256 + tid;   // float4 index in [0,2048)
    const int r = f >> 5;          // 32 float4 per row
    const int c4 = f & 31;
    float4 v = make_float4(0.f, 0.f, 0.f, 0.f);
    if (row0 + r < n) v = *(const float4*)&s[(size_t)(row0 + r) * FEATN + c4 * 4];
    uint2 pk;
    pk.x = (unsigned)f2bf(v.x) | ((unsigned)f2bf(v.y) << 16);
    pk.y = (unsigned)f2bf(v.z) | ((unsigned)f2bf(v.w) << 16);
    *(uint2*)&sA[swz(r, c4 * 4)] = pk;
  }
  // ---- stage W1t (bf16), swizzled
#pragma unroll
  for (int i = 0; i < 8; ++i) {
    const int f = i * 256 + tid;   // 16B chunk index in [0,2048)
    const int r = f >> 4;          // 16 chunks per 128-col row
    const int c8 = f & 15;
    const uint4 v = *(const uint4*)&W1t[r * 128 + c8 * 8];
    *(uint4*)&sW[swz(r, c8 * 8)] = v;
  }
  __syncthreads();

  const int arow = w * 16 + (lane & 15);
  const int kbase = (lane >> 4) * 8;
  const int drow0 = w * 16 + ((lane >> 4) << 2);
  const int dcol = lane & 15;

  // ---- GEMM1: t = silu(s @ W1 + b1)
  {
    f32x4 acc[8] = {};
#pragma unroll
    for (int ks = 0; ks < 4; ++ks) {
      const int kk = ks * 32 + kbase;
      const short8 a = *(const short8*)&sA[swz(arow, kk)];
#pragma unroll
      for (int nf = 0; nf < 8; ++nf) {
        const short8 b = *(const short8*)&sW[swz(nf * 16 + dcol, kk)];
        acc[nf] = __builtin_amdgcn_mfma_f32_16x16x32_bf16(a, b, acc[nf], 0, 0, 0);
      }
    }
#pragma unroll
    for (int nf = 0; nf < 8; ++nf) {
      const int col = nf * 16 + dcol;
      const float bias = b1[col];
#pragma unroll
      for (int r = 0; r < 4; ++r) {
        const float v = acc[nf][r] + bias;
        const float t = v / (1.0f + __expf(-v));  // silu
        sT[swz(drow0 + r, col)] = f2bf(t);
      }
    }
  }
  __syncthreads();   // all waves done with sW (W1) before overwrite

  // ---- GEMM2: h = t @ W2 + b2, in 3 chunks of 128 cols
  for (int c = 0; c < 3; ++c) {
#pragma unroll
    for (int i = 0; i < 8; ++i) {
      const int f = i * 256 + tid;
      const int r = f >> 4;
      const int c8 = f & 15;
      const uint4 v = *(const uint4*)&W2t[(size_t)(c * 128 + r) * 128 + c8 * 8];
      *(uint4*)&sW[swz(r, c8 * 8)] = v;
    }
    __syncthreads();

    f32x4 acc2[8] = {};
#pragma unroll
    for (int ks = 0; ks < 4; ++ks) {
      const int kk = ks * 32 + kbase;
      const short8 a = *(const short8*)&sT[swz(arow, kk)];
#pragma unroll
      for (int nf = 0; nf < 8; ++nf) {
        const short8 b = *(const short8*)&sW[swz(nf * 16 + dcol, kk)];
        acc2[nf] = __builtin_amdgcn_mfma_f32_16x16x32_bf16(a, b, acc2[nf], 0, 0, 0);
      }
    }
#pragma unroll
    for (int nf = 0; nf < 8; ++nf) {
      const int col = c * 128 + nf * 16 + dcol;
      const float bias = b2[col];
#pragma unroll
      for (int r = 0; r < 4; ++r) {
        const int row = row0 + drow0 + r;
        if (row < n) hbf[(size_t)row * F3 + col] = f2bf(acc2[nf][r] + bias);
      }
    }
    __syncthreads();   // before next chunk overwrites sW
  }
}

// ---------------------------------------------------------------------------
// Kernel 4: edge kernel. One thread handles 2 quads (8 outputs) of one edge:
// quads {sub, sub+48} so each store instruction is lane-contiguous.
// h gather is a REGULAR load (16x reuse per node row -> let L2 keep it);
// out store stays nontemporal (write-once 1.23 GB).
// ---------------------------------------------------------------------------
__global__ __launch_bounds__(256) void edge_kernel(
    const float* __restrict__ dist, const int* __restrict__ nbrs,
    const unsigned short* __restrict__ hbf, const unsigned short* __restrict__ tabP,
    float* __restrict__ out, int n_edges) {
  const int gid = blockIdx.x * 256 + threadIdx.x;
  const int total = n_edges * 48;
  if (gid >= total) return;
  const int e = gid / 48;
  const int sub = gid - e * 48;        // handles quads sub and sub+48

  const float d = dist[e];
  const int nbr = nbrs[2 * e + 1];

  const float inv_h = (float)(TABN - 1) / (CUT - D0);
  float x = (d - D0) * inv_h;
  x = fminf(fmaxf(x, 0.0f), 2046.9995f);
  const int i0 = (int)x;
  const float fr = x - (float)i0;

  const size_t tbase = (size_t)i0 * 96;
  const uint4 tp0 = *(const uint4*)&tabP[(tbase + sub) * 8];
  const uint4 tp1 = *(const uint4*)&tabP[(tbase + sub + 48) * 8];
  const size_t hbase = (size_t)nbr * F3;
  const u32x2 hp0 = *(const u32x2*)&hbf[hbase + sub * 4];
  const u32x2 hp1 = *(const u32x2*)&hbf[hbase + (sub + 48) * 4];

  f32x4 o0, o1;
  {
    const float t0x = bflo(tp0.x), t0y = bfhi(tp0.x);
    const float t0z = bflo(tp0.y), t0w = bfhi(tp0.y);
    const float t1x = bflo(tp0.z), t1y = bfhi(tp0.z);
    const float t1z = bflo(tp0.w), t1w = bfhi(tp0.w);
    o0.x = bflo(hp0.x) * fmaf(fr, t1x - t0x, t0x);
    o0.y = bfhi(hp0.x) * fmaf(fr, t1y - t0y, t0y);
    o0.z = bflo(hp0.y) * fmaf(fr, t1z - t0z, t0z);
    o0.w = bfhi(hp0.y) * fmaf(fr, t1w - t0w, t0w);
  }
  {
    const float t0x = bflo(tp1.x), t0y = bfhi(tp1.x);
    const float t0z = bflo(tp1.y), t0w = bfhi(tp1.y);
    const float t1x = bflo(tp1.z), t1y = bfhi(tp1.z);
    const float t1z = bflo(tp1.w), t1w = bfhi(tp1.w);
    o1.x = bflo(hp1.x) * fmaf(fr, t1x - t0x, t0x);
    o1.y = bfhi(hp1.x) * fmaf(fr, t1y - t0y, t0y);
    o1.z = bflo(hp1.y) * fmaf(fr, t1z - t0z, t0z);
    o1.w = bfhi(hp1.y) * fmaf(fr, t1w - t0w, t0w);
  }
  f32x4* obase = (f32x4*)out + (size_t)e * 96 + sub;
  __builtin_nontemporal_store(o0, obase);
  __builtin_nontemporal_store(o1, obase + 48);
}

// ---------------------------------------------------------------------------
extern "C" void kernel_launch(void* const* d_in, const int* in_sizes, int n_in,
                              void* d_out, int out_size, void* d_ws, size_t ws_size,
                              hipStream_t stream) {
  const float* s_j  = (const float*)d_in[0];
  const float* dist = (const float*)d_in[1];
  const int*   nbrs = (const int*)d_in[2];
  const float* W1   = (const float*)d_in[3];
  const float* b1   = (const float*)d_in[4];
  const float* W2   = (const float*)d_in[5];
  const float* b2   = (const float*)d_in[6];
  const float* Wd   = (const float*)d_in[7];
  const float* bd   = (const float*)d_in[8];
  float* out = (float*)d_out;

  const int n_nodes = in_sizes[0] / FEATN;
  const int n_edges = in_sizes[1];

  char* ws = (char*)d_ws;
  unsigned short* tabP = (unsigned short*)ws;                       // 3,145,728 B
  unsigned short* hbf = (unsigned short*)(ws + 3145728);            // n_nodes*384*2 B
  unsigned short* W1t = hbf + (size_t)n_nodes * F3;
  unsigned short* W2t = W1t + FEATN * FEATN;

  hipLaunchKernelGGL(table_kernel, dim3(TABN), dim3(F3), 0, stream, Wd, bd, tabP);
  hipLaunchKernelGGL(prep_kernel, dim3((FEATN * FEATN + F3 * FEATN + 255) / 256), dim3(256),
                     0, stream, W1, W2, W1t, W2t);
  hipLaunchKernelGGL(node_mfma_kernel, dim3((n_nodes + 63) / 64), dim3(256), 0, stream,
                     s_j, W1t, b1, W2t, b2, hbf, n_nodes);

  const long long total = (long long)n_edges * 48LL;
  const int blocks = (int)((total + 255) / 256);
  hipLaunchKernelGGL(edge_kernel, dim3(blocks), dim3(256), 0, stream,
                     dist, nbrs, hbf, tabP, out, n_edges);
}

// Round 6
// 315.920 us; speedup vs baseline: 2.0703x; 1.2191x over previous
//
#include <hip/hip_runtime.h>

#define FEATN 128
#define F3 384
#define NRBF 20
#define KPAD 32
#define EB 32
#define D0 0.1f
#define CUT 5.0f
#define PI_F 3.14159265358979323846f

typedef __attribute__((ext_vector_type(8))) short short8;
typedef __attribute__((ext_vector_type(4))) float f32x4;
typedef __attribute__((ext_vector_type(2))) unsigned int u32x2;

__device__ __forceinline__ unsigned short f2bf(float f) {
  unsigned int u = __float_as_uint(f);
  u += 0x7FFFu + ((u >> 16) & 1u);   // round-to-nearest-even
  return (unsigned short)(u >> 16);
}
__device__ __forceinline__ float bflo(unsigned int u) { return __uint_as_float(u << 16); }
__device__ __forceinline__ float bfhi(unsigned int u) { return __uint_as_float(u & 0xffff0000u); }

// XOR swizzle for [R][128]-bf16 LDS tiles: spreads 16B slots across banks (G4)
__device__ __forceinline__ int swz(int row, int col) {
  return row * 128 + (col ^ ((row & 7) << 3));
}

// ---------------------------------------------------------------------------
// Kernel 1: one-off weight prep:
//   W1t[n][k] = bf16(W1[k][n])          (128x128)
//   W2t[n][k] = bf16(W2[k][n])          (384x128)
//   Wdt[c][k] = bf16(Wd[k][c]), k<20; 0 for k in [20,32)   (384x32, MFMA-B ready)
// ---------------------------------------------------------------------------
__global__ __launch_bounds__(256) void prep_kernel(const float* __restrict__ W1,
                                                   const float* __restrict__ W2,
                                                   const float* __restrict__ Wd,
                                                   unsigned short* __restrict__ W1t,
                                                   unsigned short* __restrict__ W2t,
                                                   unsigned short* __restrict__ Wdt) {
  const int idx = blockIdx.x * 256 + threadIdx.x;
  if (idx < FEATN * FEATN) {
    const int nn = idx >> 7, k = idx & 127;
    W1t[idx] = f2bf(W1[k * FEATN + nn]);
  }
  const int idx2 = idx - FEATN * FEATN;
  if (idx2 >= 0 && idx2 < F3 * FEATN) {
    const int nn = idx2 >> 7, k = idx2 & 127;
    W2t[idx2] = f2bf(W2[k * F3 + nn]);
  }
  const int idx3 = idx - FEATN * FEATN - F3 * FEATN;
  if (idx3 >= 0 && idx3 < F3 * KPAD) {
    const int c = idx3 >> 5, k = idx3 & 31;
    Wdt[idx3] = (k < NRBF) ? f2bf(Wd[k * F3 + c]) : (unsigned short)0;
  }
}

// ---------------------------------------------------------------------------
// Kernel 2: fused node transform via bf16 MFMA:
//   h = silu(s @ W1 + b1) @ W2 + b2   (h stored as bf16)
// 64 rows/block, 4 waves; each wave owns a 16-row strip.
// ---------------------------------------------------------------------------
__global__ __launch_bounds__(256, 2) void node_mfma_kernel(
    const float* __restrict__ s, const unsigned short* __restrict__ W1t,
    const float* __restrict__ b1, const unsigned short* __restrict__ W2t,
    const float* __restrict__ b2, unsigned short* __restrict__ hbf, int n) {
  __shared__ unsigned short sA[64 * 128];   // 16 KB, swizzled
  __shared__ unsigned short sT[64 * 128];   // 16 KB, swizzled
  __shared__ unsigned short sW[128 * 128];  // 32 KB, swizzled (W1t, then W2t chunks)

  const int tid = threadIdx.x;
  const int w = tid >> 6;
  const int lane = tid & 63;
  const int row0 = blockIdx.x * 64;

  // ---- stage s rows (f32 -> bf16), swizzled
#pragma unroll
  for (int i = 0; i < 8; ++i) {
    const int f = i * 256 + tid;   // float4 index in [0,2048)
    const int r = f >> 5;          // 32 float4 per row
    const int c4 = f & 31;
    float4 v = make_float4(0.f, 0.f, 0.f, 0.f);
    if (row0 + r < n) v = *(const float4*)&s[(size_t)(row0 + r) * FEATN + c4 * 4];
    uint2 pk;
    pk.x = (unsigned)f2bf(v.x) | ((unsigned)f2bf(v.y) << 16);
    pk.y = (unsigned)f2bf(v.z) | ((unsigned)f2bf(v.w) << 16);
    *(uint2*)&sA[swz(r, c4 * 4)] = pk;
  }
  // ---- stage W1t (bf16), swizzled
#pragma unroll
  for (int i = 0; i < 8; ++i) {
    const int f = i * 256 + tid;   // 16B chunk index in [0,2048)
    const int r = f >> 4;          // 16 chunks per 128-col row
    const int c8 = f & 15;
    const uint4 v = *(const uint4*)&W1t[r * 128 + c8 * 8];
    *(uint4*)&sW[swz(r, c8 * 8)] = v;
  }
  __syncthreads();

  const int arow = w * 16 + (lane & 15);
  const int kbase = (lane >> 4) * 8;
  const int drow0 = w * 16 + ((lane >> 4) << 2);
  const int dcol = lane & 15;

  // ---- GEMM1: t = silu(s @ W1 + b1)
  {
    f32x4 acc[8] = {};
#pragma unroll
    for (int ks = 0; ks < 4; ++ks) {
      const int kk = ks * 32 + kbase;
      const short8 a = *(const short8*)&sA[swz(arow, kk)];
#pragma unroll
      for (int nf = 0; nf < 8; ++nf) {
        const short8 b = *(const short8*)&sW[swz(nf * 16 + dcol, kk)];
        acc[nf] = __builtin_amdgcn_mfma_f32_16x16x32_bf16(a, b, acc[nf], 0, 0, 0);
      }
    }
#pragma unroll
    for (int nf = 0; nf < 8; ++nf) {
      const int col = nf * 16 + dcol;
      const float bias = b1[col];
#pragma unroll
      for (int r = 0; r < 4; ++r) {
        const float v = acc[nf][r] + bias;
        const float t = v / (1.0f + __expf(-v));  // silu
        sT[swz(drow0 + r, col)] = f2bf(t);
      }
    }
  }
  __syncthreads();   // all waves done with sW (W1) before overwrite

  // ---- GEMM2: h = t @ W2 + b2, in 3 chunks of 128 cols
  for (int c = 0; c < 3; ++c) {
#pragma unroll
    for (int i = 0; i < 8; ++i) {
      const int f = i * 256 + tid;
      const int r = f >> 4;
      const int c8 = f & 15;
      const uint4 v = *(const uint4*)&W2t[(size_t)(c * 128 + r) * 128 + c8 * 8];
      *(uint4*)&sW[swz(r, c8 * 8)] = v;
    }
    __syncthreads();

    f32x4 acc2[8] = {};
#pragma unroll
    for (int ks = 0; ks < 4; ++ks) {
      const int kk = ks * 32 + kbase;
      const short8 a = *(const short8*)&sT[swz(arow, kk)];
#pragma unroll
      for (int nf = 0; nf < 8; ++nf) {
        const short8 b = *(const short8*)&sW[swz(nf * 16 + dcol, kk)];
        acc2[nf] = __builtin_amdgcn_mfma_f32_16x16x32_bf16(a, b, acc2[nf], 0, 0, 0);
      }
    }
#pragma unroll
    for (int nf = 0; nf < 8; ++nf) {
      const int col = c * 128 + nf * 16 + dcol;
      const float bias = b2[col];
#pragma unroll
      for (int r = 0; r < 4; ++r) {
        const int row = row0 + drow0 + r;
        if (row < n) hbf[(size_t)row * F3 + col] = f2bf(acc2[nf][r] + bias);
      }
    }
    __syncthreads();   // before next chunk overwrites sW
  }
}

// ---------------------------------------------------------------------------
// Kernel 3: fused edge kernel, EB=32 edges per 256-thread block.
// Phase 1: threads 0..31 compute per-edge env-scaled rbf (sin recurrence) -> sA.
// Phase 1b: w_s = (env*rbf) @ Wd + env*bd via 12 MFMAs/wave -> sWS (LDS bf16).
// Phase 2: out[e][j] = h[nbr[e]][j] * w_s[e][j], coalesced nt f32x4 stream.
// Removes all table traffic (was 1.23 GB of L2/L3 reads).
// ---------------------------------------------------------------------------
__global__ __launch_bounds__(256, 4) void edge_kernel(
    const float* __restrict__ dist, const int* __restrict__ nbrs,
    const unsigned short* __restrict__ hbf, const unsigned short* __restrict__ Wdt,
    const float* __restrict__ bd, float* __restrict__ out, int n_edges) {
  __shared__ unsigned short sA[EB * KPAD];   // 2 KB: A-operand (env*rbf), K-padded
  __shared__ unsigned short sWS[EB * F3];    // 24 KB: w_s per edge, bf16
  __shared__ float env_ls[EB];
  __shared__ int nbr_ls[EB];

  const int tid = threadIdx.x;
  const int e0 = blockIdx.x * EB;

  // ---- Phase 1: per-edge scalars + rbf rows (threads 0..31)
  if (tid < EB) {
    const int e = e0 + tid;
    float d = 1.0f;
    int nbr = 0;
    float sc = 0.f, cc = 1.f, env = 0.f;
    if (e < n_edges) {
      d = dist[e];
      nbr = nbrs[2 * e + 1];
      const float th = (PI_F / CUT) * d;
      __sincosf(th, &sc, &cc);
      env = (d < CUT) ? 0.5f * (cc + 1.0f) : 0.0f;
    }
    nbr_ls[tid] = nbr;
    env_ls[tid] = env;
    // rbf_k = sin(k*th)/d via recurrence; fold env in: a_k = env*sin(k*th)/d
    const float einv = env / d;
    const float twoc = 2.0f * cc;
    float skm1 = 0.f, sk = sc;
    unsigned short* arow = &sA[tid * KPAD];
#pragma unroll
    for (int k = 0; k < NRBF; ++k) {
      arow[k] = f2bf(sk * einv);
      const float nxt = twoc * sk - skm1;
      skm1 = sk;
      sk = nxt;
    }
#pragma unroll
    for (int k = NRBF; k < KPAD; ++k) arow[k] = 0;
  }
  __syncthreads();

  // ---- Phase 1b: w_s via MFMA. wave w: row-tile rt=w&1, col-half ch=w>>1.
  {
    const int wv = tid >> 6, lane = tid & 63;
    const int rt = wv & 1, ch = wv >> 1;
    const short8 a = *(const short8*)&sA[(rt * 16 + (lane & 15)) * KPAD + (lane >> 4) * 8];
    const int bl = lane & 15;
    const int kb = (lane >> 4) * 8;
    const int rbase = rt * 16 + ((lane >> 4) << 2);
    float envr[4];
#pragma unroll
    for (int r = 0; r < 4; ++r) envr[r] = env_ls[rbase + r];

#pragma unroll
    for (int ct = 0; ct < 12; ++ct) {
      const int col = ch * 192 + ct * 16 + bl;
      const short8 b = *(const short8*)&Wdt[col * KPAD + kb];   // L2-hot, 24 KB total
      f32x4 acc = {};
      acc = __builtin_amdgcn_mfma_f32_16x16x32_bf16(a, b, acc, 0, 0, 0);
      const float bdv = bd[col];
#pragma unroll
      for (int r = 0; r < 4; ++r)
        sWS[(rbase + r) * F3 + col] = f2bf(acc[r] + envr[r] * bdv);
    }
  }
  __syncthreads();

  // ---- Phase 2: multiply by gathered h, stream out (contiguous per wave)
  const size_t obase = (size_t)e0 * 96;
#pragma unroll
  for (int i = 0; i < (EB * 96) / 256; ++i) {   // 12 iterations
    const int qi = i * 256 + tid;
    const int le = qi / 96;
    const int sub = qi - le * 96;
    if (e0 + le < n_edges) {
      const int nbr = nbr_ls[le];
      const u32x2 hp = *(const u32x2*)&hbf[(size_t)nbr * F3 + sub * 4];
      const u32x2 wsv = *(const u32x2*)&sWS[le * F3 + sub * 4];
      f32x4 o;
      o.x = bflo(hp.x) * bflo(wsv.x);
      o.y = bfhi(hp.x) * bfhi(wsv.x);
      o.z = bflo(hp.y) * bflo(wsv.y);
      o.w = bfhi(hp.y) * bfhi(wsv.y);
      __builtin_nontemporal_store(o, (f32x4*)out + obase + qi);
    }
  }
}

// ---------------------------------------------------------------------------
extern "C" void kernel_launch(void* const* d_in, const int* in_sizes, int n_in,
                              void* d_out, int out_size, void* d_ws, size_t ws_size,
                              hipStream_t stream) {
  const float* s_j  = (const float*)d_in[0];
  const float* dist = (const float*)d_in[1];
  const int*   nbrs = (const int*)d_in[2];
  const float* W1   = (const float*)d_in[3];
  const float* b1   = (const float*)d_in[4];
  const float* W2   = (const float*)d_in[5];
  const float* b2   = (const float*)d_in[6];
  const float* Wd   = (const float*)d_in[7];
  const float* bd   = (const float*)d_in[8];
  float* out = (float*)d_out;

  const int n_nodes = in_sizes[0] / FEATN;
  const int n_edges = in_sizes[1];

  char* ws = (char*)d_ws;
  unsigned short* hbf = (unsigned short*)ws;                 // n_nodes*384*2 B
  unsigned short* W1t = hbf + (size_t)n_nodes * F3;
  unsigned short* W2t = W1t + FEATN * FEATN;
  unsigned short* Wdt = W2t + F3 * FEATN;

  const int prep_elems = FEATN * FEATN + F3 * FEATN + F3 * KPAD;
  hipLaunchKernelGGL(prep_kernel, dim3((prep_elems + 255) / 256), dim3(256), 0, stream,
                     W1, W2, Wd, W1t, W2t, Wdt);
  hipLaunchKernelGGL(node_mfma_kernel, dim3((n_nodes + 63) / 64), dim3(256), 0, stream,
                     s_j, W1t, b1, W2t, b2, hbf, n_nodes);
  hipLaunchKernelGGL(edge_kernel, dim3((n_edges + EB - 1) / EB), dim3(256), 0, stream,
                     dist, nbrs, hbf, Wdt, bd, out, n_edges);
}